// Round 6
// baseline (266.959 us; speedup 1.0000x reference)
//
#include <hip/hip_runtime.h>

#define F 128
#define SCANB 1024
#define NBLK 128      // partition blocks
#define MAXNB 4096    // max buckets
#define MAXBS 64      // max nodes per bucket (bshift <= 6)

typedef __attribute__((ext_vector_type(8))) short short8;
typedef __attribute__((ext_vector_type(4))) float f32x4;

static __device__ __forceinline__ short f2bf(float f) {
    union { float f; unsigned u; } v; v.f = f;
    unsigned r = v.u + 0x7FFF + ((v.u >> 16) & 1);   // round-to-nearest-even
    return (short)(r >> 16);
}
static __device__ __forceinline__ float bf_lo(unsigned u) {
    return __builtin_bit_cast(float, u << 16);
}
static __device__ __forceinline__ float bf_hi(unsigned u) {
    return __builtin_bit_cast(float, u & 0xFFFF0000u);
}

// ========== atomic-free partition: pass 1 — per-(bucket,block) counts ======
__global__ __launch_bounds__(256) void k_part_hist(
    const int* __restrict__ dst, int* __restrict__ mat,
    int n_edges, int nb, int bshift, int epb) {
    __shared__ int lh[MAXNB];
    for (int i = threadIdx.x; i < nb; i += 256) lh[i] = 0;
    __syncthreads();
    int e0 = blockIdx.x * epb;
    int e1 = min(e0 + epb, n_edges);
    for (int e = e0 + threadIdx.x; e < e1; e += 256)
        atomicAdd(&lh[dst[e] >> bshift], 1);
    __syncthreads();
    for (int i = threadIdx.x; i < nb; i += 256)
        mat[(size_t)i * NBLK + blockIdx.x] = lh[i];
}

// ========== exclusive scan (generic, used in-place on mat) =================
__global__ __launch_bounds__(SCANB) void k_scan_a(const int* in, int* out,
                                                  int* bsum, int n) {
    __shared__ int tmp[SCANB];
    int i = blockIdx.x * SCANB + threadIdx.x;
    int v = (i < n) ? in[i] : 0;
    tmp[threadIdx.x] = v;
    __syncthreads();
    for (int off = 1; off < SCANB; off <<= 1) {
        int t = (threadIdx.x >= off) ? tmp[threadIdx.x - off] : 0;
        __syncthreads();
        tmp[threadIdx.x] += t;
        __syncthreads();
    }
    if (i < n) out[i] = tmp[threadIdx.x] - v;
    if (threadIdx.x == SCANB - 1) bsum[blockIdx.x] = tmp[SCANB - 1];
}

__global__ __launch_bounds__(512) void k_scan_b(int* bsum, int nb) {
    __shared__ int tmp[512];
    int i = threadIdx.x;
    int v = (i < nb) ? bsum[i] : 0;
    tmp[i] = v;
    __syncthreads();
    for (int off = 1; off < 512; off <<= 1) {
        int t = (i >= off) ? tmp[i - off] : 0;
        __syncthreads();
        tmp[i] += t;
        __syncthreads();
    }
    if (i < nb) bsum[i] = tmp[i] - v;
}

__global__ __launch_bounds__(SCANB) void k_scan_c(int* out, const int* bsum, int n) {
    int i = blockIdx.x * SCANB + threadIdx.x;
    if (i < n) out[i] += bsum[blockIdx.x];
}

// ========== pass 2 — scatter packed edges, zero global atomics =============
__global__ __launch_bounds__(256) void k_part_scatter(
    const int* __restrict__ src, const int* __restrict__ dst,
    const int* __restrict__ mat, unsigned* __restrict__ binned,
    int n_edges, int nb, int bshift, int epb) {
    __shared__ int lbase[MAXNB];
    int e0 = blockIdx.x * epb;
    int e1 = min(e0 + epb, n_edges);
    for (int i = threadIdx.x; i < nb; i += 256)
        lbase[i] = mat[(size_t)i * NBLK + blockIdx.x];
    __syncthreads();
    for (int e = e0 + threadIdx.x; e < e1; e += 256) {
        int d = dst[e];
        int b = d >> bshift;
        int pos = atomicAdd(&lbase[b], 1);   // LDS atomic only
        binned[pos] = ((unsigned)(d & ((1 << bshift) - 1)) << 26) | (unsigned)src[e];
    }
}

// ========== pass 3 — per-bucket CSR finalize (deg/offs/esrc, all local) ====
__global__ __launch_bounds__(256) void k_bin_to_csr(
    const unsigned* __restrict__ binned, const int* __restrict__ mat,
    int* __restrict__ deg, int* __restrict__ offs, int* __restrict__ esrc,
    int n_edges, int n_nodes, int nb, int bshift) {
    __shared__ int ldeg[MAXBS], loffs[MAXBS], lcur[MAXBS];
    int b = blockIdx.x;
    int start = mat[(size_t)b * NBLK];
    int end   = (b + 1 < nb) ? mat[(size_t)(b + 1) * NBLK] : n_edges;
    int cnt = end - start;
    int base_node = b << bshift;
    int nn = min(1 << bshift, n_nodes - base_node);
    for (int i = threadIdx.x; i < nn; i += 256) { ldeg[i] = 0; lcur[i] = 0; }
    __syncthreads();
    for (int i = threadIdx.x; i < cnt; i += 256)
        atomicAdd(&ldeg[binned[start + i] >> 26], 1);
    __syncthreads();
    if (threadIdx.x == 0) {
        int run = 0;
        for (int i = 0; i < nn; ++i) { loffs[i] = run; run += ldeg[i]; }
    }
    __syncthreads();
    for (int i = threadIdx.x; i < nn; i += 256) {
        deg[base_node + i]  = ldeg[i];
        offs[base_node + i] = start + loffs[i];
    }
    for (int i = threadIdx.x; i < cnt; i += 256) {
        unsigned p = binned[start + i];
        int ln = p >> 26;
        int pos = start + loffs[ln] + atomicAdd(&lcur[ln], 1);  // LDS atomic
        esrc[pos] = (int)(p & ((1u << 26) - 1));
    }
}

// ========== fallback CSR build (direct path) ===============================
__global__ __launch_bounds__(256) void k_hist(const int* __restrict__ dst,
                                              int* __restrict__ deg, int n_edges) {
    int e = blockIdx.x * 256 + threadIdx.x;
    if (e < n_edges) atomicAdd(&deg[dst[e]], 1);
}

__global__ __launch_bounds__(256) void k_scatter_idx(
    const int* __restrict__ src, const int* __restrict__ dst,
    const int* __restrict__ offs, int* __restrict__ cursor,
    int* __restrict__ esrc, int n_edges) {
    int e = blockIdx.x * 256 + threadIdx.x;
    if (e >= n_edges) return;
    int d = dst[e];
    int pos = offs[d] + atomicAdd(&cursor[d], 1);
    esrc[pos] = src[e];
}

// ========== h (f32) -> hb (bf16 packed pairs) ==============================
__global__ __launch_bounds__(256) void k_h2b(const float* __restrict__ h,
                                             unsigned* __restrict__ hb, int total8) {
    int t = blockIdx.x * 256 + threadIdx.x;
    if (t >= total8) return;
    const float4* hp = (const float4*)h;
    float4 a = hp[t * 2], b = hp[t * 2 + 1];
    uint4 o;
    o.x = ((unsigned)(unsigned short)f2bf(a.y) << 16) | (unsigned short)f2bf(a.x);
    o.y = ((unsigned)(unsigned short)f2bf(a.w) << 16) | (unsigned short)f2bf(a.z);
    o.z = ((unsigned)(unsigned short)f2bf(b.y) << 16) | (unsigned short)f2bf(b.x);
    o.w = ((unsigned)(unsigned short)f2bf(b.w) << 16) | (unsigned short)f2bf(b.z);
    ((uint4*)hb)[t] = o;
}

// ========== FUSED: gather-sum + norm -> MFMA matmul -> LayerNorm -> ReLU ===
// Block = 256 threads (4 waves). Block handles 64 nodes; wave w owns 16.
// Gather: 4 lane-groups x 16 lanes; each group reads a whole 256B bf16 row
// with one dwordx4; 4 such loads unrolled -> 16 edges in flight per wave.
// Gathered rows staged in LDS as bf16, then MFMA + fused LN/ReLU epilogue.
__global__ __launch_bounds__(256) void k_fused(
    const unsigned* __restrict__ hb, const int* __restrict__ esrc,
    const int* __restrict__ offs, const int* __restrict__ deg,
    const float* __restrict__ w, const float* __restrict__ bias,
    const float* __restrict__ gamma, const float* __restrict__ beta,
    float* __restrict__ out, int n_nodes) {
    __shared__ short wt[128 * 136];     // W^T [col][k], padded
    __shared__ short xs[4][16][136];    // per-wave staged A rows, padded

    const int tid = threadIdx.x;
    {
        int n = tid & 127;
        for (int k = tid >> 7; k < 128; k += 2)
            wt[n * 136 + k] = f2bf(w[(size_t)k * 128 + n]);
    }

    const int wv = tid >> 6;
    const int l  = tid & 63;
    const int g  = l >> 4;        // lane group: which row within a 4-row load
    const int q  = l & 15;        // 16B chunk within the 256B row
    const int lr = l & 15;        // MFMA fragment row / C col
    const int lk = l >> 4;        // MFMA k-subgroup / C row group

    float bs[8], gm[8], bt[8];
    #pragma unroll
    for (int n = 0; n < 8; ++n) {
        int c = n * 16 + lr;
        bs[n] = bias[c]; gm[n] = gamma[c]; bt[n] = beta[c];
    }

    const int base = blockIdx.x * 64;

    // ---- gather phase: wave wv gathers its 16 nodes into xs[wv] ----
    for (int i = 0; i < 16; ++i) {
        int node = base + wv * 16 + i;
        int start = 0, dn = 0;
        if (node < n_nodes) { start = offs[node]; dn = deg[node]; }
        int end = start + dn;

        float a0=0,a1=0,a2=0,a3=0,a4=0,a5=0,a6=0,a7=0;
        for (int e0 = start; e0 < end; e0 += 16) {
            #pragma unroll
            for (int u = 0; u < 4; ++u) {
                int e = e0 + u * 4 + g;
                if (e < end) {
                    int s = esrc[e];
                    uint4 v = *((const uint4*)(hb + (size_t)s * 64 + q * 4));
                    a0 += bf_lo(v.x); a1 += bf_hi(v.x);
                    a2 += bf_lo(v.y); a3 += bf_hi(v.y);
                    a4 += bf_lo(v.z); a5 += bf_hi(v.z);
                    a6 += bf_lo(v.w); a7 += bf_hi(v.w);
                }
            }
        }
        // combine the 4 lane-groups (masks 16 and 32)
        #pragma unroll
        for (int m = 16; m <= 32; m <<= 1) {
            a0 += __shfl_xor(a0, m); a1 += __shfl_xor(a1, m);
            a2 += __shfl_xor(a2, m); a3 += __shfl_xor(a3, m);
            a4 += __shfl_xor(a4, m); a5 += __shfl_xor(a5, m);
            a6 += __shfl_xor(a6, m); a7 += __shfl_xor(a7, m);
        }
        float nv = dn > 0 ? 1.0f / (float)dn : 0.0f;
        if (l < 16) {
            uint4 o;
            o.x = ((unsigned)(unsigned short)f2bf(a1 * nv) << 16) | (unsigned short)f2bf(a0 * nv);
            o.y = ((unsigned)(unsigned short)f2bf(a3 * nv) << 16) | (unsigned short)f2bf(a2 * nv);
            o.z = ((unsigned)(unsigned short)f2bf(a5 * nv) << 16) | (unsigned short)f2bf(a4 * nv);
            o.w = ((unsigned)(unsigned short)f2bf(a7 * nv) << 16) | (unsigned short)f2bf(a6 * nv);
            *((uint4*)&xs[wv][i][q * 8]) = o;
        }
    }
    __syncthreads();   // wt + all xs visible

    // ---- MFMA phase: wave wv computes its 16 rows x 128 cols ----
    short8 af[4];
    #pragma unroll
    for (int kk = 0; kk < 4; ++kk)
        af[kk] = *(const short8*)&xs[wv][lr][kk * 32 + lk * 8];

    f32x4 acc[8];
    #pragma unroll
    for (int n = 0; n < 8; ++n) acc[n] = f32x4{0, 0, 0, 0};

    #pragma unroll
    for (int kk = 0; kk < 4; ++kk) {
        const int kb = kk * 32 + lk * 8;
        #pragma unroll
        for (int n = 0; n < 8; ++n) {
            short8 bfr = *(const short8*)(&wt[(n * 16 + lr) * 136 + kb]);
            acc[n] = __builtin_amdgcn_mfma_f32_16x16x32_bf16(af[kk], bfr, acc[n], 0, 0, 0);
        }
    }

    // bias + LN stats; C layout: col = n*16+lr, row = lk*4 + r
    float s4[4] = {0,0,0,0}, q4[4] = {0,0,0,0};
    #pragma unroll
    for (int n = 0; n < 8; ++n)
        #pragma unroll
        for (int r = 0; r < 4; ++r) {
            float v = acc[n][r] + bs[n];
            acc[n][r] = v;
            s4[r] += v; q4[r] += v * v;
        }
    #pragma unroll
    for (int m = 1; m < 16; m <<= 1)
        #pragma unroll
        for (int r = 0; r < 4; ++r) {
            s4[r] += __shfl_xor(s4[r], m);
            q4[r] += __shfl_xor(q4[r], m);
        }

    #pragma unroll
    for (int r = 0; r < 4; ++r) {
        float mu   = s4[r] * (1.0f / F);
        float var  = q4[r] * (1.0f / F) - mu * mu;
        float rstd = rsqrtf(var + 1e-5f);
        int rw = base + wv * 16 + lk * 4 + r;
        if (rw < n_nodes) {
            #pragma unroll
            for (int n = 0; n < 8; ++n) {
                float y = (acc[n][r] - mu) * rstd * gm[n] + bt[n];
                out[(size_t)rw * F + n * 16 + lr] = fmaxf(y, 0.0f);
            }
        }
    }
}

extern "C" void kernel_launch(void* const* d_in, const int* in_sizes, int n_in,
                              void* d_out, int out_size, void* d_ws, size_t ws_size,
                              hipStream_t stream) {
    const float* h      = (const float*)d_in[0];
    const float* weight = (const float*)d_in[1];
    const float* bias   = (const float*)d_in[2];
    const float* gamma  = (const float*)d_in[3];
    const float* beta   = (const float*)d_in[4];
    const int*   src    = (const int*)d_in[5];
    const int*   dst    = (const int*)d_in[6];

    const int n_nodes = in_sizes[0] / F;
    const int n_edges = in_sizes[5];

    float* x = (float*)d_out;

    // bucket shift: bucket = dst >> bshift; need nb <= MAXNB and bshift <= 6
    int bshift = 5;
    while (bshift <= 6 && ((n_nodes + (1 << bshift) - 1) >> bshift) > MAXNB) ++bshift;
    const int nb = (n_nodes + (1 << bshift) - 1) >> bshift;
    const bool shift_ok = (((n_nodes + (1 << bshift) - 1) >> bshift) <= MAXNB) &&
                          (n_nodes <= (1 << 26));

    // workspace (ints): deg[N] | offs[N] | esrc[E] | hb[N*64 u32] |
    //   new path tail:  bsum[512] | mat[nb*NBLK] | binned[E u32]
    //   fallback tail:  bsum[512] | cursor[N]
    int* deg    = (int*)d_ws;
    int* offs   = deg + n_nodes;
    int* esrc   = offs + n_nodes;
    unsigned* hb = (unsigned*)(esrc + n_edges);
    int* bsum   = (int*)(hb + (size_t)n_nodes * 64);
    int* mat    = bsum + 512;
    unsigned* binned = (unsigned*)(mat + (size_t)nb * NBLK);
    int* cursor = mat;   // fallback reuses mat slot

    size_t need_common = ((size_t)2 * n_nodes + (size_t)n_edges + 512) * sizeof(int)
                       + (size_t)n_nodes * 64 * sizeof(unsigned);
    size_t need_new  = need_common + ((size_t)nb * NBLK + (size_t)n_edges) * sizeof(int);
    size_t need_fall = need_common + (size_t)n_nodes * sizeof(int);
    bool use_new = shift_ok && ws_size >= need_new;

    // bf16 h copy
    {
        int total8 = n_nodes * F / 8;
        k_h2b<<<(total8 + 255) / 256, 256, 0, stream>>>(h, hb, total8);
    }

    if (use_new) {
        const int epb = (n_edges + NBLK - 1) / NBLK;
        const int len = nb * NBLK;
        const int nscan = (len + SCANB - 1) / SCANB;
        k_part_hist<<<NBLK, 256, 0, stream>>>(dst, mat, n_edges, nb, bshift, epb);
        k_scan_a<<<nscan, SCANB, 0, stream>>>(mat, mat, bsum, len);
        k_scan_b<<<1, 512, 0, stream>>>(bsum, nscan);
        k_scan_c<<<nscan, SCANB, 0, stream>>>(mat, bsum, len);
        k_part_scatter<<<NBLK, 256, 0, stream>>>(src, dst, mat, binned,
                                                 n_edges, nb, bshift, epb);
        k_bin_to_csr<<<nb, 256, 0, stream>>>(binned, mat, deg, offs, esrc,
                                             n_edges, n_nodes, nb, bshift);
    } else if (ws_size >= need_fall) {
        const int nscan = (n_nodes + SCANB - 1) / SCANB;
        hipMemsetAsync(deg, 0, (size_t)n_nodes * sizeof(int), stream);
        hipMemsetAsync(cursor, 0, (size_t)n_nodes * sizeof(int), stream);
        k_hist<<<(n_edges + 255) / 256, 256, 0, stream>>>(dst, deg, n_edges);
        k_scan_a<<<nscan, SCANB, 0, stream>>>(deg, offs, bsum, n_nodes);
        k_scan_b<<<1, 512, 0, stream>>>(bsum, nscan);
        k_scan_c<<<nscan, SCANB, 0, stream>>>(offs, bsum, n_nodes);
        k_scatter_idx<<<(n_edges + 255) / 256, 256, 0, stream>>>(
            src, dst, offs, cursor, esrc, n_edges);
    }

    int fblocks = (n_nodes + 63) / 64;
    k_fused<<<fblocks, 256, 0, stream>>>(hb, esrc, offs, deg,
                                         weight, bias, gamma, beta, x, n_nodes);
}

// Round 7
// 181.643 us; speedup vs baseline: 1.4697x; 1.4697x over previous
//
#include <hip/hip_runtime.h>

#define F 128
#define SCANB 1024
#define NBLK 128      // partition blocks
#define MAXNB 4096    // max buckets
#define MAXBS 64      // max nodes per bucket (bshift <= 6)

typedef __attribute__((ext_vector_type(8))) short short8;
typedef __attribute__((ext_vector_type(4))) float f32x4;

static __device__ __forceinline__ short f2bf(float f) {
    union { float f; unsigned u; } v; v.f = f;
    unsigned r = v.u + 0x7FFF + ((v.u >> 16) & 1);   // round-to-nearest-even
    return (short)(r >> 16);
}
static __device__ __forceinline__ float bf_lo(unsigned u) {
    return __builtin_bit_cast(float, u << 16);
}
static __device__ __forceinline__ float bf_hi(unsigned u) {
    return __builtin_bit_cast(float, u & 0xFFFF0000u);
}

// ========== atomic-free partition: pass 1 — per-(bucket,block) counts ======
__global__ __launch_bounds__(256) void k_part_hist(
    const int* __restrict__ dst, int* __restrict__ mat,
    int n_edges, int nb, int bshift, int epb) {
    __shared__ int lh[MAXNB];
    for (int i = threadIdx.x; i < nb; i += 256) lh[i] = 0;
    __syncthreads();
    int e0 = blockIdx.x * epb;
    int e1 = min(e0 + epb, n_edges);
    for (int e = e0 + threadIdx.x; e < e1; e += 256)
        atomicAdd(&lh[dst[e] >> bshift], 1);
    __syncthreads();
    for (int i = threadIdx.x; i < nb; i += 256)
        mat[(size_t)i * NBLK + blockIdx.x] = lh[i];
}

// ========== exclusive scan (generic, used in-place on mat) =================
__global__ __launch_bounds__(SCANB) void k_scan_a(const int* in, int* out,
                                                  int* bsum, int n) {
    __shared__ int tmp[SCANB];
    int i = blockIdx.x * SCANB + threadIdx.x;
    int v = (i < n) ? in[i] : 0;
    tmp[threadIdx.x] = v;
    __syncthreads();
    for (int off = 1; off < SCANB; off <<= 1) {
        int t = (threadIdx.x >= off) ? tmp[threadIdx.x - off] : 0;
        __syncthreads();
        tmp[threadIdx.x] += t;
        __syncthreads();
    }
    if (i < n) out[i] = tmp[threadIdx.x] - v;
    if (threadIdx.x == SCANB - 1) bsum[blockIdx.x] = tmp[SCANB - 1];
}

__global__ __launch_bounds__(512) void k_scan_b(int* bsum, int nb) {
    __shared__ int tmp[512];
    int i = threadIdx.x;
    int v = (i < nb) ? bsum[i] : 0;
    tmp[i] = v;
    __syncthreads();
    for (int off = 1; off < 512; off <<= 1) {
        int t = (i >= off) ? tmp[i - off] : 0;
        __syncthreads();
        tmp[i] += t;
        __syncthreads();
    }
    if (i < nb) bsum[i] = tmp[i] - v;
}

__global__ __launch_bounds__(SCANB) void k_scan_c(int* out, const int* bsum, int n) {
    int i = blockIdx.x * SCANB + threadIdx.x;
    if (i < n) out[i] += bsum[blockIdx.x];
}

// ========== pass 2 — scatter packed edges, zero global atomics =============
__global__ __launch_bounds__(256) void k_part_scatter(
    const int* __restrict__ src, const int* __restrict__ dst,
    const int* __restrict__ mat, unsigned* __restrict__ binned,
    int n_edges, int nb, int bshift, int epb) {
    __shared__ int lbase[MAXNB];
    int e0 = blockIdx.x * epb;
    int e1 = min(e0 + epb, n_edges);
    for (int i = threadIdx.x; i < nb; i += 256)
        lbase[i] = mat[(size_t)i * NBLK + blockIdx.x];
    __syncthreads();
    for (int e = e0 + threadIdx.x; e < e1; e += 256) {
        int d = dst[e];
        int b = d >> bshift;
        int pos = atomicAdd(&lbase[b], 1);   // LDS atomic only
        binned[pos] = ((unsigned)(d & ((1 << bshift) - 1)) << 26) | (unsigned)src[e];
    }
}

// ========== pass 3 — per-bucket CSR finalize (deg/offs/esrc, all local) ====
__global__ __launch_bounds__(256) void k_bin_to_csr(
    const unsigned* __restrict__ binned, const int* __restrict__ mat,
    int* __restrict__ deg, int* __restrict__ offs, int* __restrict__ esrc,
    int n_edges, int n_nodes, int nb, int bshift) {
    __shared__ int ldeg[MAXBS], loffs[MAXBS], lcur[MAXBS];
    int b = blockIdx.x;
    int start = mat[(size_t)b * NBLK];
    int end   = (b + 1 < nb) ? mat[(size_t)(b + 1) * NBLK] : n_edges;
    int cnt = end - start;
    int base_node = b << bshift;
    int nn = min(1 << bshift, n_nodes - base_node);
    for (int i = threadIdx.x; i < nn; i += 256) { ldeg[i] = 0; lcur[i] = 0; }
    __syncthreads();
    for (int i = threadIdx.x; i < cnt; i += 256)
        atomicAdd(&ldeg[binned[start + i] >> 26], 1);
    __syncthreads();
    if (threadIdx.x == 0) {
        int run = 0;
        for (int i = 0; i < nn; ++i) { loffs[i] = run; run += ldeg[i]; }
    }
    __syncthreads();
    for (int i = threadIdx.x; i < nn; i += 256) {
        deg[base_node + i]  = ldeg[i];
        offs[base_node + i] = start + loffs[i];
    }
    for (int i = threadIdx.x; i < cnt; i += 256) {
        unsigned p = binned[start + i];
        int ln = p >> 26;
        int pos = start + loffs[ln] + atomicAdd(&lcur[ln], 1);  // LDS atomic
        esrc[pos] = (int)(p & ((1u << 26) - 1));
    }
}

// ========== fallback CSR build (direct path) ===============================
__global__ __launch_bounds__(256) void k_hist(const int* __restrict__ dst,
                                              int* __restrict__ deg, int n_edges) {
    int e = blockIdx.x * 256 + threadIdx.x;
    if (e < n_edges) atomicAdd(&deg[dst[e]], 1);
}

__global__ __launch_bounds__(256) void k_scatter_idx(
    const int* __restrict__ src, const int* __restrict__ dst,
    const int* __restrict__ offs, int* __restrict__ cursor,
    int* __restrict__ esrc, int n_edges) {
    int e = blockIdx.x * 256 + threadIdx.x;
    if (e >= n_edges) return;
    int d = dst[e];
    int pos = offs[d] + atomicAdd(&cursor[d], 1);
    esrc[pos] = src[e];
}

// ========== dense GEMM: hW = h @ W, output bf16-packed =====================
// Block = 256 threads (4 waves); wave wv owns rows base+wv*16 .. +15.
// W^T staged bf16 in LDS (padded 136); C bounced through f32 LDS (padded 132)
// so the bf16 global write is fully coalesced (uint4 per 16 lanes per row).
__global__ __launch_bounds__(256) void k_gemm_hw(
    const float* __restrict__ h, const float* __restrict__ w,
    unsigned* __restrict__ hb, int n_nodes) {
    __shared__ short wt[128 * 136];     // wt[col][k]
    __shared__ float xs[4][16][132];    // per-wave C bounce

    const int tid = threadIdx.x;
    {
        int n = tid & 127;
        for (int k = tid >> 7; k < 128; k += 2)
            wt[n * 136 + k] = f2bf(w[(size_t)k * 128 + n]);
    }
    __syncthreads();

    const int wv = tid >> 6;
    const int l  = tid & 63;
    const int lr = l & 15;
    const int lk = l >> 4;
    const int q  = l & 15;

    for (int base = blockIdx.x * 64; base < n_nodes; base += gridDim.x * 64) {
        const int row = base + wv * 16 + lr;
        const bool valid = row < n_nodes;

        short8 af[4];
        #pragma unroll
        for (int kk = 0; kk < 4; ++kk) {
            int k0 = kk * 32 + lk * 8;
            float4 a0{0,0,0,0}, a1{0,0,0,0};
            if (valid) {
                a0 = *(const float4*)(h + (size_t)row * F + k0);
                a1 = *(const float4*)(h + (size_t)row * F + k0 + 4);
            }
            af[kk] = short8{ f2bf(a0.x), f2bf(a0.y), f2bf(a0.z), f2bf(a0.w),
                             f2bf(a1.x), f2bf(a1.y), f2bf(a1.z), f2bf(a1.w) };
        }

        f32x4 acc[8];
        #pragma unroll
        for (int n = 0; n < 8; ++n) acc[n] = f32x4{0, 0, 0, 0};

        #pragma unroll
        for (int kk = 0; kk < 4; ++kk) {
            const int kb = kk * 32 + lk * 8;
            #pragma unroll
            for (int n = 0; n < 8; ++n) {
                short8 bfr = *(const short8*)(&wt[(n * 16 + lr) * 136 + kb]);
                acc[n] = __builtin_amdgcn_mfma_f32_16x16x32_bf16(af[kk], bfr, acc[n], 0, 0, 0);
            }
        }

        // bounce C through LDS (wave-local region; wave-synchronous)
        #pragma unroll
        for (int n = 0; n < 8; ++n)
            #pragma unroll
            for (int r = 0; r < 4; ++r)
                xs[wv][lk * 4 + r][n * 16 + lr] = acc[n][r];

        #pragma unroll
        for (int rr = 0; rr < 4; ++rr) {
            int lrow = rr * 4 + lk;
            int grow = base + wv * 16 + lrow;
            float4 a = *(const float4*)&xs[wv][lrow][q * 8];
            float4 b = *(const float4*)&xs[wv][lrow][q * 8 + 4];
            uint4 o;
            o.x = ((unsigned)(unsigned short)f2bf(a.y) << 16) | (unsigned short)f2bf(a.x);
            o.y = ((unsigned)(unsigned short)f2bf(a.w) << 16) | (unsigned short)f2bf(a.z);
            o.z = ((unsigned)(unsigned short)f2bf(b.y) << 16) | (unsigned short)f2bf(b.x);
            o.w = ((unsigned)(unsigned short)f2bf(b.w) << 16) | (unsigned short)f2bf(b.z);
            if (grow < n_nodes)
                ((uint4*)hb)[(size_t)grow * 16 + q] = o;
        }
        // no __syncthreads needed: xs region is per-wave, reuse is in-order
    }
}

// ========== gather hW rows + norm + bias + LayerNorm + ReLU ================
// One 64-lane wave per node; lane holds features (2*lane, 2*lane+1).
__global__ __launch_bounds__(256) void k_gather_ln(
    const unsigned* __restrict__ hb, const int* __restrict__ esrc,
    const int* __restrict__ offs, const int* __restrict__ deg,
    const float* __restrict__ bias, const float* __restrict__ gamma,
    const float* __restrict__ beta, float* __restrict__ out, int n_nodes) {
    int t = blockIdx.x * 256 + threadIdx.x;
    int node = t >> 6;
    int lane = t & 63;
    if (node >= n_nodes) return;
    int start = offs[node];
    int dn = deg[node];
    float ax = 0.0f, ay = 0.0f;
    int i = 0;
    for (; i + 8 <= dn; i += 8) {
        #pragma unroll
        for (int u = 0; u < 8; ++u) {
            int s = esrc[start + i + u];
            unsigned v = hb[(size_t)s * 64 + lane];
            ax += bf_lo(v); ay += bf_hi(v);
        }
    }
    for (; i < dn; ++i) {
        int s = esrc[start + i];
        unsigned v = hb[(size_t)s * 64 + lane];
        ax += bf_lo(v); ay += bf_hi(v);
    }
    float nv = dn > 0 ? 1.0f / (float)dn : 0.0f;
    float fx = ax * nv + bias[2 * lane];
    float fy = ay * nv + bias[2 * lane + 1];

    float s = fx + fy, q = fx * fx + fy * fy;
    #pragma unroll
    for (int m = 1; m < 64; m <<= 1) {
        s += __shfl_xor(s, m);
        q += __shfl_xor(q, m);
    }
    float mu   = s * (1.0f / F);
    float var  = q * (1.0f / F) - mu * mu;
    float rstd = rsqrtf(var + 1e-5f);

    float y0 = fmaxf((fx - mu) * rstd * gamma[2 * lane]     + beta[2 * lane],     0.0f);
    float y1 = fmaxf((fy - mu) * rstd * gamma[2 * lane + 1] + beta[2 * lane + 1], 0.0f);
    ((float2*)out)[(size_t)node * 64 + lane] = make_float2(y0, y1);
}

extern "C" void kernel_launch(void* const* d_in, const int* in_sizes, int n_in,
                              void* d_out, int out_size, void* d_ws, size_t ws_size,
                              hipStream_t stream) {
    const float* h      = (const float*)d_in[0];
    const float* weight = (const float*)d_in[1];
    const float* bias   = (const float*)d_in[2];
    const float* gamma  = (const float*)d_in[3];
    const float* beta   = (const float*)d_in[4];
    const int*   src    = (const int*)d_in[5];
    const int*   dst    = (const int*)d_in[6];

    const int n_nodes = in_sizes[0] / F;
    const int n_edges = in_sizes[5];

    float* x = (float*)d_out;

    // bucket shift: bucket = dst >> bshift; need nb <= MAXNB and bshift <= 6
    int bshift = 5;
    while (bshift <= 6 && ((n_nodes + (1 << bshift) - 1) >> bshift) > MAXNB) ++bshift;
    const int nb = (n_nodes + (1 << bshift) - 1) >> bshift;
    const bool shift_ok = (((n_nodes + (1 << bshift) - 1) >> bshift) <= MAXNB) &&
                          (n_nodes <= (1 << 26));

    // workspace (ints): deg[N] | offs[N] | esrc[E] | hb[N*64 u32] |
    //   new path tail:  bsum[512] | mat[nb*NBLK] | binned[E u32]
    //   fallback tail:  bsum[512] | cursor[N]
    int* deg    = (int*)d_ws;
    int* offs   = deg + n_nodes;
    int* esrc   = offs + n_nodes;
    unsigned* hb = (unsigned*)(esrc + n_edges);
    int* bsum   = (int*)(hb + (size_t)n_nodes * 64);
    int* mat    = bsum + 512;
    unsigned* binned = (unsigned*)(mat + (size_t)nb * NBLK);
    int* cursor = mat;   // fallback reuses mat slot

    size_t need_common = ((size_t)2 * n_nodes + (size_t)n_edges + 512) * sizeof(int)
                       + (size_t)n_nodes * 64 * sizeof(unsigned);
    size_t need_new  = need_common + ((size_t)nb * NBLK + (size_t)n_edges) * sizeof(int);
    size_t need_fall = need_common + (size_t)n_nodes * sizeof(int);
    bool use_new = shift_ok && ws_size >= need_new;

    // dense GEMM first: hb = bf16(h @ W)
    {
        int gb = (n_nodes + 63) / 64;
        k_gemm_hw<<<gb, 256, 0, stream>>>(h, weight, hb, n_nodes);
    }

    if (use_new) {
        const int epb = (n_edges + NBLK - 1) / NBLK;
        const int len = nb * NBLK;
        const int nscan = (len + SCANB - 1) / SCANB;
        k_part_hist<<<NBLK, 256, 0, stream>>>(dst, mat, n_edges, nb, bshift, epb);
        k_scan_a<<<nscan, SCANB, 0, stream>>>(mat, mat, bsum, len);
        k_scan_b<<<1, 512, 0, stream>>>(bsum, nscan);
        k_scan_c<<<nscan, SCANB, 0, stream>>>(mat, bsum, len);
        k_part_scatter<<<NBLK, 256, 0, stream>>>(src, dst, mat, binned,
                                                 n_edges, nb, bshift, epb);
        k_bin_to_csr<<<nb, 256, 0, stream>>>(binned, mat, deg, offs, esrc,
                                             n_edges, n_nodes, nb, bshift);
    } else if (ws_size >= need_fall) {
        const int nscan = (n_nodes + SCANB - 1) / SCANB;
        hipMemsetAsync(deg, 0, (size_t)n_nodes * sizeof(int), stream);
        hipMemsetAsync(cursor, 0, (size_t)n_nodes * sizeof(int), stream);
        k_hist<<<(n_edges + 255) / 256, 256, 0, stream>>>(dst, deg, n_edges);
        k_scan_a<<<nscan, SCANB, 0, stream>>>(deg, offs, bsum, n_nodes);
        k_scan_b<<<1, 512, 0, stream>>>(bsum, nscan);
        k_scan_c<<<nscan, SCANB, 0, stream>>>(offs, bsum, n_nodes);
        k_scatter_idx<<<(n_edges + 255) / 256, 256, 0, stream>>>(
            src, dst, offs, cursor, esrc, n_edges);
    }

    int gblocks = (int)(((size_t)n_nodes * 64 + 255) / 256);
    k_gather_ln<<<gblocks, 256, 0, stream>>>(hb, esrc, offs, deg,
                                             bias, gamma, beta, x, n_nodes);
}